// Round 1
// baseline (139.220 us; speedup 1.0000x reference)
//
#include <hip/hip_runtime.h>
#include <hip/hip_bf16.h>
#include <float.h>

// Problem constants
constexpr int B   = 2;
constexpr int N   = 16384;
constexpr int S   = 4096;
constexpr int INC = 256;
constexpr int OUTC = 128;

// ---------------------------------------------------------------------------
// K1/K2: row-block GEMM  out[row, col] = sum_k f[row,k]*W[k,col] + bias[col]
// Block: 256 threads = 128 cols x 2 row-groups; 16 rows per block.
// ---------------------------------------------------------------------------
template <int K>
__global__ __launch_bounds__(256) void k_gemm(const float* __restrict__ f,
                                              const float* __restrict__ W,
                                              const float* __restrict__ bias,
                                              float* __restrict__ outf) {
    __shared__ __align__(16) float sf[16 * K];
    const int rowbase = blockIdx.x * 16;

    // Stage 16 input rows (contiguous) into LDS, float4-vectorized.
    const float4* src4 = reinterpret_cast<const float4*>(f + (size_t)rowbase * K);
    float4* sf4 = reinterpret_cast<float4*>(sf);
    for (int i = threadIdx.x; i < 4 * K; i += 256) sf4[i] = src4[i];
    __syncthreads();

    const int col = threadIdx.x & 127;
    const int rg  = threadIdx.x >> 7;   // 0..1, handles rows rg*8 .. rg*8+7

    float acc[8] = {0.f,0.f,0.f,0.f,0.f,0.f,0.f,0.f};

    for (int k = 0; k < K; k += 4) {
        float w0 = W[(k + 0) * OUTC + col];
        float w1 = W[(k + 1) * OUTC + col];
        float w2 = W[(k + 2) * OUTC + col];
        float w3 = W[(k + 3) * OUTC + col];
        #pragma unroll
        for (int r = 0; r < 8; ++r) {
            const float4 fv = *reinterpret_cast<const float4*>(&sf[(rg * 8 + r) * K + k]);
            float a = acc[r];
            a = fmaf(fv.x, w0, a);
            a = fmaf(fv.y, w1, a);
            a = fmaf(fv.z, w2, a);
            a = fmaf(fv.w, w3, a);
            acc[r] = a;
        }
    }

    const float bb = bias[col];
    #pragma unroll
    for (int r = 0; r < 8; ++r)
        outf[(size_t)(rowbase + rg * 8 + r) * OUTC + col] = acc[r] + bb;
}

// ---------------------------------------------------------------------------
// K3: 3-NN + inverse-distance interpolation, added onto ori_f already in out.
// Block: 256 threads = 64 query points x 4 S-splits. down xyz (+sumsq) in LDS.
// Per-split skew of 2 float4s (8 words) decorrelates banks across the 4
// distinct per-wave addresses -> conflict-free ds_read_b128.
// ---------------------------------------------------------------------------
#define INS3(dd, ss)                                                        \
    {                                                                       \
        const bool c0 = (dd) < d0, c1 = (dd) < d1, c2 = (dd) < d2v;         \
        d2v = c1 ? d1 : (c2 ? (dd) : d2v);                                  \
        i2  = c1 ? i1 : (c2 ? (ss) : i2);                                   \
        d1  = c0 ? d0 : (c1 ? (dd) : d1);                                   \
        i1  = c0 ? i0 : (c1 ? (ss) : i1);                                   \
        d0  = c0 ? (dd) : d0;                                               \
        i0  = c0 ? (ss) : i0;                                               \
    }

__global__ __launch_bounds__(256) void k_interp(const float4* __restrict__ dxyzp,
                                                const float4* __restrict__ oxyzp,
                                                const float*  __restrict__ downf,
                                                float*        __restrict__ out) {
    // 4 splits x (1024 + 2 skew) float4
    __shared__ float4 sx[4 * 1026];
    __shared__ int    si[64 * 3];
    __shared__ float  sw[64 * 3];

    const int b     = blockIdx.x >> 8;           // 256 blocks per batch
    const int pbase = (blockIdx.x & 255) * 64;

    // Stage down xyz, replacing 4th component with x^2+y^2+z^2 (numpy order).
    const float4* dp = dxyzp + (size_t)b * S;
    for (int i = threadIdx.x; i < S; i += 256) {
        float4 v = dp[i];
        v.w = __fadd_rn(__fadd_rn(__fmul_rn(v.x, v.x), __fmul_rn(v.y, v.y)),
                        __fmul_rn(v.z, v.z));
        sx[(i >> 10) * 1026 + (i & 1023)] = v;
    }
    __syncthreads();

    const int split = threadIdx.x & 3;
    const int p     = threadIdx.x >> 2;

    const float4 o = oxyzp[(size_t)b * N + pbase + p];
    const float sumo = __fadd_rn(__fadd_rn(__fmul_rn(o.x, o.x), __fmul_rn(o.y, o.y)),
                                 __fmul_rn(o.z, o.z));

    float d0 = FLT_MAX, d1 = FLT_MAX, d2v = FLT_MAX;
    int   i0 = 0, i1 = 0, i2 = 0;

    const float4* basep = &sx[split * 1026];
    const int sbase = split << 10;

    #pragma unroll 4
    for (int i = 0; i < 1024; ++i) {
        const float4 q = basep[i];
        const float dot = __fadd_rn(__fadd_rn(__fmul_rn(o.x, q.x), __fmul_rn(o.y, q.y)),
                                    __fmul_rn(o.z, q.z));
        const float dd = __fsub_rn(__fadd_rn(sumo, q.w), __fmul_rn(2.0f, dot));
        const int  s  = sbase + i;
        INS3(dd, s);
    }

    // Butterfly merge across the 4 splits; lane with split==0 ends correct
    // (neighbor indices always higher -> strict '<' keeps lower index on tie).
    #pragma unroll
    for (int m = 1; m <= 2; m <<= 1) {
        const float nd0 = __shfl_xor(d0, m, 64);
        const float nd1 = __shfl_xor(d1, m, 64);
        const float nd2 = __shfl_xor(d2v, m, 64);
        const int   ni0 = __shfl_xor(i0, m, 64);
        const int   ni1 = __shfl_xor(i1, m, 64);
        const int   ni2 = __shfl_xor(i2, m, 64);
        INS3(nd0, ni0);
        INS3(nd1, ni1);
        INS3(nd2, ni2);
    }

    if (split == 0) {
        const float r0 = 1.0f / (d0  + 1e-8f);
        const float r1 = 1.0f / (d1  + 1e-8f);
        const float r2 = 1.0f / (d2v + 1e-8f);
        const float rs = __fadd_rn(__fadd_rn(r0, r1), r2);
        si[p * 3 + 0] = i0;
        si[p * 3 + 1] = i1;
        si[p * 3 + 2] = i2;
        sw[p * 3 + 0] = r0 / rs;
        sw[p * 3 + 1] = r1 / rs;
        sw[p * 3 + 2] = r2 / rs;
    }
    __syncthreads();

    // Gather + interpolate: 64 points x 128 channels, 256 threads.
    const int ch = threadIdx.x & 127;
    const int hf = threadIdx.x >> 7;
    const float* df = downf + (size_t)b * S * OUTC;
    float* ob = out + ((size_t)b * N + pbase) * OUTC;

    for (int pp = hf; pp < 64; pp += 2) {
        const int   j0 = si[pp * 3 + 0];
        const int   j1 = si[pp * 3 + 1];
        const int   j2 = si[pp * 3 + 2];
        const float w0 = sw[pp * 3 + 0];
        const float w1 = sw[pp * 3 + 1];
        const float w2 = sw[pp * 3 + 2];
        const float g = __fadd_rn(
            __fadd_rn(__fmul_rn(w0, df[(size_t)j0 * OUTC + ch]),
                      __fmul_rn(w1, df[(size_t)j1 * OUTC + ch])),
            __fmul_rn(w2, df[(size_t)j2 * OUTC + ch]));
        ob[(size_t)pp * OUTC + ch] += g;
    }
}

// ---------------------------------------------------------------------------

extern "C" void kernel_launch(void* const* d_in, const int* in_sizes, int n_in,
                              void* d_out, int out_size, void* d_ws, size_t ws_size,
                              hipStream_t stream) {
    const float* dxyzp = (const float*)d_in[0];   // (B,S,4)
    const float* dfeat = (const float*)d_in[1];   // (B,S,256)
    const float* oxyzp = (const float*)d_in[2];   // (B,N,4)
    const float* ofeat = (const float*)d_in[3];   // (B,N,128)
    const float* W1    = (const float*)d_in[4];   // (256,128)
    const float* b1    = (const float*)d_in[5];   // (128)
    const float* W2    = (const float*)d_in[6];   // (128,128)
    const float* b2    = (const float*)d_in[7];   // (128)

    float* out   = (float*)d_out;                 // (B,N,128)
    float* downf = (float*)d_ws;                  // (B,S,128) scratch: 4 MB

    // down_f = down_features @ W1 + b1  -> workspace
    k_gemm<INC><<<(B * S) / 16, 256, 0, stream>>>(dfeat, W1, b1, downf);
    // ori_f = ori_features @ W2 + b2    -> out
    k_gemm<OUTC><<<(B * N) / 16, 256, 0, stream>>>(ofeat, W2, b2, out);
    // out += 3-NN inverse-distance interpolation of down_f
    k_interp<<<B * (N / 64), 256, 0, stream>>>(
        (const float4*)dxyzp, (const float4*)oxyzp, downf, out);
}

// Round 3
// 139.000 us; speedup vs baseline: 1.0016x; 1.0016x over previous
//
#include <hip/hip_runtime.h>
#include <hip/hip_bf16.h>
#include <float.h>

// Problem constants
constexpr int B   = 2;
constexpr int N   = 16384;
constexpr int S   = 4096;
constexpr int INC = 256;
constexpr int OUTC = 128;

// ---------------------------------------------------------------------------
// K1/K2: row-block GEMM  out[row, col] = sum_k f[row,k]*W[k,col] + bias[col]
// Block: 256 threads = 128 cols x 2 row-groups; 16 rows per block.
// (unchanged from the passing R1 kernel)
// ---------------------------------------------------------------------------
template <int K>
__global__ __launch_bounds__(256) void k_gemm(const float* __restrict__ f,
                                              const float* __restrict__ W,
                                              const float* __restrict__ bias,
                                              float* __restrict__ outf) {
    __shared__ __align__(16) float sf[16 * K];
    const int rowbase = blockIdx.x * 16;

    const float4* src4 = reinterpret_cast<const float4*>(f + (size_t)rowbase * K);
    float4* sf4 = reinterpret_cast<float4*>(sf);
    for (int i = threadIdx.x; i < 4 * K; i += 256) sf4[i] = src4[i];
    __syncthreads();

    const int col = threadIdx.x & 127;
    const int rg  = threadIdx.x >> 7;

    float acc[8] = {0.f,0.f,0.f,0.f,0.f,0.f,0.f,0.f};

    for (int k = 0; k < K; k += 4) {
        float w0 = W[(k + 0) * OUTC + col];
        float w1 = W[(k + 1) * OUTC + col];
        float w2 = W[(k + 2) * OUTC + col];
        float w3 = W[(k + 3) * OUTC + col];
        #pragma unroll
        for (int r = 0; r < 8; ++r) {
            const float4 fv = *reinterpret_cast<const float4*>(&sf[(rg * 8 + r) * K + k]);
            float a = acc[r];
            a = fmaf(fv.x, w0, a);
            a = fmaf(fv.y, w1, a);
            a = fmaf(fv.z, w2, a);
            a = fmaf(fv.w, w3, a);
            acc[r] = a;
        }
    }

    const float bb = bias[col];
    #pragma unroll
    for (int r = 0; r < 8; ++r)
        outf[(size_t)(rowbase + rg * 8 + r) * OUTC + col] = acc[r] + bb;
}

// ---------------------------------------------------------------------------
// K3: 3-NN + inverse-distance interpolation, added onto ori_f already in out.
// EXACT R1 geometry (passed): 512 blocks x 256 threads, 64 query points per
// block, split = tid&3 over 4 contiguous candidate ranges of 1024.
//
// Arithmetic deltas vs R1 (each proven-equivalent):
//  - staged candidates are PRE-DOUBLED (2x,2y,2z,sumsq): (2qx)*ox == 2*(qx*ox)
//    bit-exactly, so dd = (sumo+sumq) - dot2 matches numpy's
//    (sumo+sumq) - 2*dot bit-for-bit.
//  - sorted-insert values via min/max (fuses to v_med3_f32), indices via
//    selects with strict '<' (stable: per-lane stream is ascending-index).
//  - butterfly merge uses LEXICOGRAPHIC (value, index) compare, so tie
//    stability no longer depends on split index ordering at all.
// ---------------------------------------------------------------------------
#define INS3M(dd, ss)                                                       \
    {                                                                       \
        const bool c0 = (dd) < d0, c1 = (dd) < d1, c2 = (dd) < d2v;         \
        i2  = c1 ? i1 : (c2 ? (ss) : i2);                                   \
        i1  = c0 ? i0 : (c1 ? (ss) : i1);                                   \
        i0  = c0 ? (ss) : i0;                                               \
        d2v = fminf(fmaxf((dd), d1), d2v);                                  \
        d1  = fminf(fmaxf((dd), d0), d1);                                   \
        d0  = fminf(d0, (dd));                                              \
    }

#define INS3L(dd, ss)                                                       \
    {                                                                       \
        const bool c0 = ((dd) < d0)  | (((dd) == d0)  & ((ss) < i0));       \
        const bool c1 = ((dd) < d1)  | (((dd) == d1)  & ((ss) < i1));       \
        const bool c2 = ((dd) < d2v) | (((dd) == d2v) & ((ss) < i2));       \
        i2  = c1 ? i1 : (c2 ? (ss) : i2);                                   \
        i1  = c0 ? i0 : (c1 ? (ss) : i1);                                   \
        i0  = c0 ? (ss) : i0;                                               \
        d2v = c1 ? d1 : (c2 ? (dd) : d2v);                                  \
        d1  = c0 ? d0 : (c1 ? (dd) : d1);                                   \
        d0  = c0 ? (dd) : d0;                                               \
    }

__global__ __launch_bounds__(256) void k_interp(const float4* __restrict__ dxyzp,
                                                const float4* __restrict__ oxyzp,
                                                const float*  __restrict__ downf,
                                                float*        __restrict__ out) {
    // 4 splits x (1024 + 2 skew) float4
    __shared__ float4 sx[4 * 1026];
    __shared__ int    si[64 * 3];
    __shared__ float  sw[64 * 3];

    const int b     = blockIdx.x >> 8;           // 256 blocks per batch
    const int pbase = (blockIdx.x & 255) * 64;

    // Stage: (2x, 2y, 2z, x^2+y^2+z^2); sumsq in numpy order from ORIGINAL
    // coords; doubling is exact (x2 commutes with round-to-nearest).
    const float4* dp = dxyzp + (size_t)b * S;
    for (int i = threadIdx.x; i < S; i += 256) {
        float4 v = dp[i];
        const float ss = __fadd_rn(__fadd_rn(__fmul_rn(v.x, v.x), __fmul_rn(v.y, v.y)),
                                   __fmul_rn(v.z, v.z));
        float4 w;
        w.x = v.x + v.x;
        w.y = v.y + v.y;
        w.z = v.z + v.z;
        w.w = ss;
        sx[(i >> 10) * 1026 + (i & 1023)] = w;
    }
    __syncthreads();

    const int split = threadIdx.x & 3;
    const int p     = threadIdx.x >> 2;

    const float4 o = oxyzp[(size_t)b * N + pbase + p];
    const float sumo = __fadd_rn(__fadd_rn(__fmul_rn(o.x, o.x), __fmul_rn(o.y, o.y)),
                                 __fmul_rn(o.z, o.z));

    float d0 = FLT_MAX, d1 = FLT_MAX, d2v = FLT_MAX;
    int   i0 = 0, i1 = 0, i2 = 0;

    const float4* basep = &sx[split * 1026];
    const int sbase = split << 10;

    #pragma unroll 4
    for (int i = 0; i < 1024; ++i) {
        const float4 q = basep[i];
        // dot2 == 2*dot bit-exactly (q.xyz pre-doubled)
        const float dot2 = __fadd_rn(__fadd_rn(__fmul_rn(q.x, o.x), __fmul_rn(q.y, o.y)),
                                     __fmul_rn(q.z, o.z));
        const float dd = __fsub_rn(__fadd_rn(sumo, q.w), dot2);
        const int  s  = sbase + i;
        INS3M(dd, s);
    }

    // Butterfly merge across the 4 splits, lexicographic -> every lane ends
    // with the stable top-3 regardless of index-range direction.
    #pragma unroll
    for (int m = 1; m <= 2; m <<= 1) {
        const float nd0 = __shfl_xor(d0, m, 64);
        const float nd1 = __shfl_xor(d1, m, 64);
        const float nd2 = __shfl_xor(d2v, m, 64);
        const int   ni0 = __shfl_xor(i0, m, 64);
        const int   ni1 = __shfl_xor(i1, m, 64);
        const int   ni2 = __shfl_xor(i2, m, 64);
        INS3L(nd0, ni0);
        INS3L(nd1, ni1);
        INS3L(nd2, ni2);
    }

    if (split == 0) {
        const float r0 = 1.0f / (d0  + 1e-8f);
        const float r1 = 1.0f / (d1  + 1e-8f);
        const float r2 = 1.0f / (d2v + 1e-8f);
        const float rs = __fadd_rn(__fadd_rn(r0, r1), r2);
        si[p * 3 + 0] = i0;
        si[p * 3 + 1] = i1;
        si[p * 3 + 2] = i2;
        sw[p * 3 + 0] = r0 / rs;
        sw[p * 3 + 1] = r1 / rs;
        sw[p * 3 + 2] = r2 / rs;
    }
    __syncthreads();

    // Gather + interpolate: 64 points x 128 channels, 256 threads.
    const int ch = threadIdx.x & 127;
    const int hf = threadIdx.x >> 7;
    const float* df = downf + (size_t)b * S * OUTC;
    float* ob = out + ((size_t)b * N + pbase) * OUTC;

    for (int pp = hf; pp < 64; pp += 2) {
        const int   j0 = si[pp * 3 + 0];
        const int   j1 = si[pp * 3 + 1];
        const int   j2 = si[pp * 3 + 2];
        const float w0 = sw[pp * 3 + 0];
        const float w1 = sw[pp * 3 + 1];
        const float w2 = sw[pp * 3 + 2];
        const float g = __fadd_rn(
            __fadd_rn(__fmul_rn(w0, df[(size_t)j0 * OUTC + ch]),
                      __fmul_rn(w1, df[(size_t)j1 * OUTC + ch])),
            __fmul_rn(w2, df[(size_t)j2 * OUTC + ch]));
        ob[(size_t)pp * OUTC + ch] += g;
    }
}

// ---------------------------------------------------------------------------

extern "C" void kernel_launch(void* const* d_in, const int* in_sizes, int n_in,
                              void* d_out, int out_size, void* d_ws, size_t ws_size,
                              hipStream_t stream) {
    const float* dxyzp = (const float*)d_in[0];   // (B,S,4)
    const float* dfeat = (const float*)d_in[1];   // (B,S,256)
    const float* oxyzp = (const float*)d_in[2];   // (B,N,4)
    const float* ofeat = (const float*)d_in[3];   // (B,N,128)
    const float* W1    = (const float*)d_in[4];   // (256,128)
    const float* b1    = (const float*)d_in[5];   // (128)
    const float* W2    = (const float*)d_in[6];   // (128,128)
    const float* b2    = (const float*)d_in[7];   // (128)

    float* out   = (float*)d_out;                 // (B,N,128)
    float* downf = (float*)d_ws;                  // (B,S,128) scratch: 4 MB

    // down_f = down_features @ W1 + b1  -> workspace
    k_gemm<INC><<<(B * S) / 16, 256, 0, stream>>>(dfeat, W1, b1, downf);
    // ori_f = ori_features @ W2 + b2    -> out
    k_gemm<OUTC><<<(B * N) / 16, 256, 0, stream>>>(ofeat, W2, b2, out);
    // out += 3-NN inverse-distance interpolation of down_f
    k_interp<<<B * (N / 64), 256, 0, stream>>>(
        (const float4*)dxyzp, (const float4*)oxyzp, downf, out);
}

// Round 5
// 128.648 us; speedup vs baseline: 1.0822x; 1.0805x over previous
//
#include <hip/hip_runtime.h>
#include <hip/hip_bf16.h>
#include <float.h>

// Problem constants
constexpr int B   = 2;
constexpr int N   = 16384;
constexpr int S   = 4096;
constexpr int INC = 256;
constexpr int OUTC = 128;

// ---------------------------------------------------------------------------
// K1/K2: row-block GEMM (unchanged from passing R1/R3).
// ---------------------------------------------------------------------------
template <int K>
__global__ __launch_bounds__(256) void k_gemm(const float* __restrict__ f,
                                              const float* __restrict__ W,
                                              const float* __restrict__ bias,
                                              float* __restrict__ outf) {
    __shared__ __align__(16) float sf[16 * K];
    const int rowbase = blockIdx.x * 16;

    const float4* src4 = reinterpret_cast<const float4*>(f + (size_t)rowbase * K);
    float4* sf4 = reinterpret_cast<float4*>(sf);
    for (int i = threadIdx.x; i < 4 * K; i += 256) sf4[i] = src4[i];
    __syncthreads();

    const int col = threadIdx.x & 127;
    const int rg  = threadIdx.x >> 7;

    float acc[8] = {0.f,0.f,0.f,0.f,0.f,0.f,0.f,0.f};

    for (int k = 0; k < K; k += 4) {
        float w0 = W[(k + 0) * OUTC + col];
        float w1 = W[(k + 1) * OUTC + col];
        float w2 = W[(k + 2) * OUTC + col];
        float w3 = W[(k + 3) * OUTC + col];
        #pragma unroll
        for (int r = 0; r < 8; ++r) {
            const float4 fv = *reinterpret_cast<const float4*>(&sf[(rg * 8 + r) * K + k]);
            float a = acc[r];
            a = fmaf(fv.x, w0, a);
            a = fmaf(fv.y, w1, a);
            a = fmaf(fv.z, w2, a);
            a = fmaf(fv.w, w3, a);
            acc[r] = a;
        }
    }

    const float bb = bias[col];
    #pragma unroll
    for (int r = 0; r < 8; ++r)
        outf[(size_t)(rowbase + rg * 8 + r) * OUTC + col] = acc[r] + bb;
}

// ---------------------------------------------------------------------------
// K3 — BISECT BUILD: R4 geometry MINUS dual accumulator streams.
//   grid: 1024 blocks (B x 512), 32 queries/block, 256 threads (4 waves).
//   lane: sp = lane&7 (8 candidate sub-ranges), qs = lane>>3, slot = wave*8+qs.
//   Candidates staged in TWO chunks of 2048 (LDS ~33.7 KB -> 4 blocks/CU).
//   Chunk laid out as 8 sub-arrays of 256 (+1 skew float4, stride 257):
//   start banks s*4 mod 32 -> 8 distinct bank-quads, conflict-free b128.
//   Each lane scans ONE stream: 256 candidates/chunk, 512 total, ascending
//   global index -> strict-'<' INS3M insert is tie-stable (R3-proven).
//   Butterfly m=1,2,4 with LEXICOGRAPHIC INS3L (R3-proven, order-independent).
// Staged candidates PRE-DOUBLED (2x,2y,2z,sumsq): bit-exact vs numpy
// (x2 commutes with RN; validated by R3 pass).
// ---------------------------------------------------------------------------
#define INS3M(d0, d1, d2, i0, i1, i2, dd, ss)                               \
    {                                                                       \
        const bool c0 = (dd) < d0, c1 = (dd) < d1, c2 = (dd) < d2;          \
        i2 = c1 ? i1 : (c2 ? (ss) : i2);                                    \
        i1 = c0 ? i0 : (c1 ? (ss) : i1);                                    \
        i0 = c0 ? (ss) : i0;                                                \
        d2 = fminf(fmaxf((dd), d1), d2);                                    \
        d1 = fminf(fmaxf((dd), d0), d1);                                    \
        d0 = fminf(d0, (dd));                                               \
    }

#define INS3L(d0, d1, d2, i0, i1, i2, dd, ss)                               \
    {                                                                       \
        const bool c0 = ((dd) < d0) | (((dd) == d0) & ((ss) < i0));         \
        const bool c1 = ((dd) < d1) | (((dd) == d1) & ((ss) < i1));         \
        const bool c2 = ((dd) < d2) | (((dd) == d2) & ((ss) < i2));         \
        i2 = c1 ? i1 : (c2 ? (ss) : i2);                                    \
        i1 = c0 ? i0 : (c1 ? (ss) : i1);                                    \
        i0 = c0 ? (ss) : i0;                                                \
        d2 = c1 ? d1 : (c2 ? (dd) : d2);                                    \
        d1 = c0 ? d0 : (c1 ? (dd) : d1);                                    \
        d0 = c0 ? (dd) : d0;                                                \
    }

__global__ __launch_bounds__(256) void k_interp(const float4* __restrict__ dxyzp,
                                                const float4* __restrict__ oxyzp,
                                                const float*  __restrict__ downf,
                                                float*        __restrict__ out) {
    // 8 sub-ranges x (256 + 1 skew) float4 = 32896 B
    __shared__ float4 sx[8 * 257];
    __shared__ int    si[32 * 3];
    __shared__ float  sw[32 * 3];

    const int b     = blockIdx.x >> 9;            // 512 blocks per batch
    const int qbase = (blockIdx.x & 511) * 32;

    const int lane = threadIdx.x & 63;
    const int wave = threadIdx.x >> 6;
    const int sp   = lane & 7;
    const int qs   = lane >> 3;
    const int slot = wave * 8 + qs;               // 0..31 within block

    const float4 o = oxyzp[(size_t)b * N + qbase + slot];
    const float sumo = __fadd_rn(__fadd_rn(__fmul_rn(o.x, o.x), __fmul_rn(o.y, o.y)),
                                 __fmul_rn(o.z, o.z));

    float a0 = FLT_MAX, a1 = FLT_MAX, a2 = FLT_MAX;
    int   ai0 = 0, ai1 = 0, ai2 = 0;

    const float4* dpb = dxyzp + (size_t)b * S;

    for (int c = 0; c < 2; ++c) {
        if (c > 0) __syncthreads();               // all waves done with prev chunk

        // Stage chunk c: (2x, 2y, 2z, x^2+y^2+z^2); doubling is exact.
        const float4* dpc = dpb + c * 2048;
        for (int j = threadIdx.x; j < 2048; j += 256) {
            float4 v = dpc[j];
            const float ss = __fadd_rn(__fadd_rn(__fmul_rn(v.x, v.x), __fmul_rn(v.y, v.y)),
                                       __fmul_rn(v.z, v.z));
            float4 w;
            w.x = v.x + v.x;
            w.y = v.y + v.y;
            w.z = v.z + v.z;
            w.w = ss;
            sx[(j >> 8) * 257 + (j & 255)] = w;
        }
        __syncthreads();

        const float4* base = &sx[sp * 257];
        const int g0 = c * 2048 + sp * 256;       // global idx base, ascending

        #pragma unroll 4
        for (int i = 0; i < 256; ++i) {
            const float4 q = base[i];
            const float dot2 = __fadd_rn(__fadd_rn(__fmul_rn(q.x, o.x), __fmul_rn(q.y, o.y)),
                                         __fmul_rn(q.z, o.z));
            const float dd = __fsub_rn(__fadd_rn(sumo, q.w), dot2);
            INS3M(a0, a1, a2, ai0, ai1, ai2, dd, g0 + i);
        }
    }

    // Butterfly merge across the 8 sp-groups, lexicographic.
    #pragma unroll
    for (int m = 1; m <= 4; m <<= 1) {
        const float nd0 = __shfl_xor(a0, m, 64);
        const float nd1 = __shfl_xor(a1, m, 64);
        const float nd2 = __shfl_xor(a2, m, 64);
        const int   ni0 = __shfl_xor(ai0, m, 64);
        const int   ni1 = __shfl_xor(ai1, m, 64);
        const int   ni2 = __shfl_xor(ai2, m, 64);
        INS3L(a0, a1, a2, ai0, ai1, ai2, nd0, ni0);
        INS3L(a0, a1, a2, ai0, ai1, ai2, nd1, ni1);
        INS3L(a0, a1, a2, ai0, ai1, ai2, nd2, ni2);
    }

    if (sp == 0) {
        const float r0 = 1.0f / (a0 + 1e-8f);
        const float r1 = 1.0f / (a1 + 1e-8f);
        const float r2 = 1.0f / (a2 + 1e-8f);
        const float rs = __fadd_rn(__fadd_rn(r0, r1), r2);
        si[slot * 3 + 0] = ai0;
        si[slot * 3 + 1] = ai1;
        si[slot * 3 + 2] = ai2;
        sw[slot * 3 + 0] = r0 / rs;
        sw[slot * 3 + 1] = r1 / rs;
        sw[slot * 3 + 2] = r2 / rs;
    }
    __syncthreads();

    // Gather + interpolate: 32 points x 128 channels, 256 threads.
    const int ch = threadIdx.x & 127;
    const int hf = threadIdx.x >> 7;
    const float* df = downf + (size_t)b * S * OUTC;
    float* ob = out + ((size_t)b * N + qbase) * OUTC;

    for (int pp = hf; pp < 32; pp += 2) {
        const int   j0 = si[pp * 3 + 0];
        const int   j1 = si[pp * 3 + 1];
        const int   j2 = si[pp * 3 + 2];
        const float w0 = sw[pp * 3 + 0];
        const float w1 = sw[pp * 3 + 1];
        const float w2 = sw[pp * 3 + 2];
        const float g = __fadd_rn(
            __fadd_rn(__fmul_rn(w0, df[(size_t)j0 * OUTC + ch]),
                      __fmul_rn(w1, df[(size_t)j1 * OUTC + ch])),
            __fmul_rn(w2, df[(size_t)j2 * OUTC + ch]));
        ob[(size_t)pp * OUTC + ch] += g;
    }
}

// ---------------------------------------------------------------------------

extern "C" void kernel_launch(void* const* d_in, const int* in_sizes, int n_in,
                              void* d_out, int out_size, void* d_ws, size_t ws_size,
                              hipStream_t stream) {
    const float* dxyzp = (const float*)d_in[0];   // (B,S,4)
    const float* dfeat = (const float*)d_in[1];   // (B,S,256)
    const float* oxyzp = (const float*)d_in[2];   // (B,N,4)
    const float* ofeat = (const float*)d_in[3];   // (B,N,128)
    const float* W1    = (const float*)d_in[4];   // (256,128)
    const float* b1    = (const float*)d_in[5];   // (128)
    const float* W2    = (const float*)d_in[6];   // (128,128)
    const float* b2    = (const float*)d_in[7];   // (128)

    float* out   = (float*)d_out;                 // (B,N,128)
    float* downf = (float*)d_ws;                  // (B,S,128) scratch: 4 MB

    // down_f = down_features @ W1 + b1  -> workspace
    k_gemm<INC><<<(B * S) / 16, 256, 0, stream>>>(dfeat, W1, b1, downf);
    // ori_f = ori_features @ W2 + b2    -> out
    k_gemm<OUTC><<<(B * N) / 16, 256, 0, stream>>>(ofeat, W2, b2, out);
    // out += 3-NN inverse-distance interpolation of down_f
    k_interp<<<B * (N / 32), 256, 0, stream>>>(
        (const float4*)dxyzp, (const float4*)oxyzp, downf, out);
}

// Round 6
// 115.979 us; speedup vs baseline: 1.2004x; 1.1092x over previous
//
#include <hip/hip_runtime.h>
#include <hip/hip_bf16.h>
#include <float.h>

// Problem constants
constexpr int B   = 2;
constexpr int N   = 16384;
constexpr int S   = 4096;
constexpr int INC = 256;
constexpr int OUTC = 128;

typedef short short4_t __attribute__((ext_vector_type(4)));
typedef short short8_t __attribute__((ext_vector_type(8)));
typedef float f32x4    __attribute__((ext_vector_type(4)));

__device__ __forceinline__ unsigned short f2bf(float f) {
    unsigned u = __builtin_bit_cast(unsigned, f);
    u += 0x7fffu + ((u >> 16) & 1u);          // round-to-nearest-even
    return (unsigned short)(u >> 16);
}

// ---------------------------------------------------------------------------
// MFMA GEMM: out[M,128] = f[M,K] @ W[K,128] + bias, bf16 compute, fp32 accum.
// Block: 256 threads (4 waves); wave w owns cols [32w, 32w+32) -> 2 col-frags.
// ROWS rows/block; MF = ROWS/16 row-frags; K-loop in steps of 32.
// W staged bf16 row-major in LDS once -> B-frags hoisted to registers for the
// whole block -> LDS reused for the XOR-swizzled bf16 A-tile (T2: row stride
// K*2 B is bank-degenerate; byte ^= (row&7)<<4 spreads 8 rows over 8 slots).
// Fragment maps (m89-verified family): A[l&15][(l>>4)*8+r],
// B[(l>>4)*8+r][l&15], D[(l>>4)*4+r][l&15].
// ---------------------------------------------------------------------------
template <int K, int ROWS>
__global__ __launch_bounds__(256) void k_mfma(const float* __restrict__ f,
                                              const float* __restrict__ W,
                                              const float* __restrict__ bias,
                                              float* __restrict__ outf) {
    constexpr int MF = ROWS / 16;             // row fragments per wave
    constexpr int KS = K / 32;                // k steps
    __shared__ __align__(16) short smem[K * 128];   // W stage, then A tile

    const int tid  = threadIdx.x;
    const int lane = tid & 63;
    const int wv   = tid >> 6;
    const int rowbase = blockIdx.x * ROWS;
    const int lo16 = lane & 15;
    const int hi8  = (lane >> 4) * 8;

    // ---- stage W (bf16, row-major [K][128]) ----
    const float4* w4 = reinterpret_cast<const float4*>(W);
    for (int n = tid; n < K * 32; n += 256) {       // K*128/4 float4s
        const float4 u = w4[n];
        short4_t s = { (short)f2bf(u.x), (short)f2bf(u.y),
                       (short)f2bf(u.z), (short)f2bf(u.w) };
        *reinterpret_cast<short4_t*>(&smem[n * 4]) = s;
    }
    __syncthreads();

    // ---- build B fragments in registers (live for the whole block) ----
    short8_t bf[KS][2];
    #pragma unroll
    for (int ks = 0; ks < KS; ++ks) {
        #pragma unroll
        for (int c = 0; c < 2; ++c) {
            const int col = wv * 32 + c * 16 + lo16;
            #pragma unroll
            for (int r = 0; r < 8; ++r)
                bf[ks][c][r] = smem[(ks * 32 + hi8 + r) * 128 + col];
        }
    }
    __syncthreads();                                 // W area now dead

    // ---- stage A tile (bf16, [ROWS][K], XOR-swizzled) ----
    const float4* a4 = reinterpret_cast<const float4*>(f + (size_t)rowbase * K);
    for (int n = tid; n < ROWS * K / 8; n += 256) {
        const int row   = n / (K / 8);
        const int k8    = (n % (K / 8)) * 8;
        const int base4 = (row * K + k8) >> 2;
        const float4 u = a4[base4];
        const float4 v = a4[base4 + 1];
        short8_t s = { (short)f2bf(u.x), (short)f2bf(u.y), (short)f2bf(u.z), (short)f2bf(u.w),
                       (short)f2bf(v.x), (short)f2bf(v.y), (short)f2bf(v.z), (short)f2bf(v.w) };
        const int idx = (row * K + k8) ^ ((row & 7) << 3);   // short-index XOR
        *reinterpret_cast<short8_t*>(&smem[idx]) = s;
    }
    __syncthreads();

    // ---- MFMA main loop ----
    f32x4 acc[MF][2];
    #pragma unroll
    for (int m = 0; m < MF; ++m) {
        #pragma unroll
        for (int c = 0; c < 2; ++c) acc[m][c] = (f32x4){0.f, 0.f, 0.f, 0.f};
    }

    const int axor = (lane & 7) << 3;   // row&7 == lane&7 since row = m*16+lo16
    #pragma unroll
    for (int ks = 0; ks < KS; ++ks) {
        #pragma unroll
        for (int m = 0; m < MF; ++m) {
            const int aidx = ((m * 16 + lo16) * K + ks * 32 + hi8) ^ axor;
            const short8_t af = *reinterpret_cast<const short8_t*>(&smem[aidx]);
            acc[m][0] = __builtin_amdgcn_mfma_f32_16x16x32_bf16(af, bf[ks][0], acc[m][0], 0, 0, 0);
            acc[m][1] = __builtin_amdgcn_mfma_f32_16x16x32_bf16(af, bf[ks][1], acc[m][1], 0, 0, 0);
        }
    }

    // ---- epilogue: D[(l>>4)*4+r][l&15] + bias ----
    #pragma unroll
    for (int c = 0; c < 2; ++c) {
        const int col = wv * 32 + c * 16 + lo16;
        const float bb = bias[col];
        #pragma unroll
        for (int m = 0; m < MF; ++m) {
            #pragma unroll
            for (int r = 0; r < 4; ++r) {
                const int row = rowbase + m * 16 + (lane >> 4) * 4 + r;
                outf[(size_t)row * 128 + col] = acc[m][c][r] + bb;
            }
        }
    }
}

// ---------------------------------------------------------------------------
// K3 — UNCHANGED from passing R5 build (bit-exact fp32 selection path).
//   grid: 1024 blocks (B x 512), 32 queries/block, 256 threads (4 waves).
//   lane: sp = lane&7 (8 candidate sub-ranges), qs = lane>>3, slot = wave*8+qs.
//   Candidates staged in TWO chunks of 2048 (LDS ~33 KB -> 4 blocks/CU).
//   Chunk laid out as 8 sub-arrays of 256 (+1 skew float4, stride 257).
//   Single top-3 stream per lane; butterfly m=1,2,4 lexicographic.
// ---------------------------------------------------------------------------
#define INS3M(d0, d1, d2, i0, i1, i2, dd, ss)                               \
    {                                                                       \
        const bool c0 = (dd) < d0, c1 = (dd) < d1, c2 = (dd) < d2;          \
        i2 = c1 ? i1 : (c2 ? (ss) : i2);                                    \
        i1 = c0 ? i0 : (c1 ? (ss) : i1);                                    \
        i0 = c0 ? (ss) : i0;                                                \
        d2 = fminf(fmaxf((dd), d1), d2);                                    \
        d1 = fminf(fmaxf((dd), d0), d1);                                    \
        d0 = fminf(d0, (dd));                                               \
    }

#define INS3L(d0, d1, d2, i0, i1, i2, dd, ss)                               \
    {                                                                       \
        const bool c0 = ((dd) < d0) | (((dd) == d0) & ((ss) < i0));         \
        const bool c1 = ((dd) < d1) | (((dd) == d1) & ((ss) < i1));         \
        const bool c2 = ((dd) < d2) | (((dd) == d2) & ((ss) < i2));         \
        i2 = c1 ? i1 : (c2 ? (ss) : i2);                                    \
        i1 = c0 ? i0 : (c1 ? (ss) : i1);                                    \
        i0 = c0 ? (ss) : i0;                                                \
        d2 = c1 ? d1 : (c2 ? (dd) : d2);                                    \
        d1 = c0 ? d0 : (c1 ? (dd) : d1);                                    \
        d0 = c0 ? (dd) : d0;                                                \
    }

__global__ __launch_bounds__(256) void k_interp(const float4* __restrict__ dxyzp,
                                                const float4* __restrict__ oxyzp,
                                                const float*  __restrict__ downf,
                                                float*        __restrict__ out) {
    // 8 sub-ranges x (256 + 1 skew) float4 = 32896 B
    __shared__ float4 sx[8 * 257];
    __shared__ int    si[32 * 3];
    __shared__ float  sw[32 * 3];

    const int b     = blockIdx.x >> 9;            // 512 blocks per batch
    const int qbase = (blockIdx.x & 511) * 32;

    const int lane = threadIdx.x & 63;
    const int wave = threadIdx.x >> 6;
    const int sp   = lane & 7;
    const int qs   = lane >> 3;
    const int slot = wave * 8 + qs;               // 0..31 within block

    const float4 o = oxyzp[(size_t)b * N + qbase + slot];
    const float sumo = __fadd_rn(__fadd_rn(__fmul_rn(o.x, o.x), __fmul_rn(o.y, o.y)),
                                 __fmul_rn(o.z, o.z));

    float a0 = FLT_MAX, a1 = FLT_MAX, a2 = FLT_MAX;
    int   ai0 = 0, ai1 = 0, ai2 = 0;

    const float4* dpb = dxyzp + (size_t)b * S;

    for (int c = 0; c < 2; ++c) {
        if (c > 0) __syncthreads();               // all waves done with prev chunk

        // Stage chunk c: (2x, 2y, 2z, x^2+y^2+z^2); doubling is exact.
        const float4* dpc = dpb + c * 2048;
        for (int j = threadIdx.x; j < 2048; j += 256) {
            float4 v = dpc[j];
            const float ss = __fadd_rn(__fadd_rn(__fmul_rn(v.x, v.x), __fmul_rn(v.y, v.y)),
                                       __fmul_rn(v.z, v.z));
            float4 w;
            w.x = v.x + v.x;
            w.y = v.y + v.y;
            w.z = v.z + v.z;
            w.w = ss;
            sx[(j >> 8) * 257 + (j & 255)] = w;
        }
        __syncthreads();

        const float4* base = &sx[sp * 257];
        const int g0 = c * 2048 + sp * 256;       // global idx base, ascending

        #pragma unroll 4
        for (int i = 0; i < 256; ++i) {
            const float4 q = base[i];
            const float dot2 = __fadd_rn(__fadd_rn(__fmul_rn(q.x, o.x), __fmul_rn(q.y, o.y)),
                                         __fmul_rn(q.z, o.z));
            const float dd = __fsub_rn(__fadd_rn(sumo, q.w), dot2);
            INS3M(a0, a1, a2, ai0, ai1, ai2, dd, g0 + i);
        }
    }

    // Butterfly merge across the 8 sp-groups, lexicographic.
    #pragma unroll
    for (int m = 1; m <= 4; m <<= 1) {
        const float nd0 = __shfl_xor(a0, m, 64);
        const float nd1 = __shfl_xor(a1, m, 64);
        const float nd2 = __shfl_xor(a2, m, 64);
        const int   ni0 = __shfl_xor(ai0, m, 64);
        const int   ni1 = __shfl_xor(ai1, m, 64);
        const int   ni2 = __shfl_xor(ai2, m, 64);
        INS3L(a0, a1, a2, ai0, ai1, ai2, nd0, ni0);
        INS3L(a0, a1, a2, ai0, ai1, ai2, nd1, ni1);
        INS3L(a0, a1, a2, ai0, ai1, ai2, nd2, ni2);
    }

    if (sp == 0) {
        const float r0 = 1.0f / (a0 + 1e-8f);
        const float r1 = 1.0f / (a1 + 1e-8f);
        const float r2 = 1.0f / (a2 + 1e-8f);
        const float rs = __fadd_rn(__fadd_rn(r0, r1), r2);
        si[slot * 3 + 0] = ai0;
        si[slot * 3 + 1] = ai1;
        si[slot * 3 + 2] = ai2;
        sw[slot * 3 + 0] = r0 / rs;
        sw[slot * 3 + 1] = r1 / rs;
        sw[slot * 3 + 2] = r2 / rs;
    }
    __syncthreads();

    // Gather + interpolate: 32 points x 128 channels, 256 threads.
    const int ch = threadIdx.x & 127;
    const int hf = threadIdx.x >> 7;
    const float* df = downf + (size_t)b * S * OUTC;
    float* ob = out + ((size_t)b * N + qbase) * OUTC;

    for (int pp = hf; pp < 32; pp += 2) {
        const int   j0 = si[pp * 3 + 0];
        const int   j1 = si[pp * 3 + 1];
        const int   j2 = si[pp * 3 + 2];
        const float w0 = sw[pp * 3 + 0];
        const float w1 = sw[pp * 3 + 1];
        const float w2 = sw[pp * 3 + 2];
        const float g = __fadd_rn(
            __fadd_rn(__fmul_rn(w0, df[(size_t)j0 * OUTC + ch]),
                      __fmul_rn(w1, df[(size_t)j1 * OUTC + ch])),
            __fmul_rn(w2, df[(size_t)j2 * OUTC + ch]));
        ob[(size_t)pp * OUTC + ch] += g;
    }
}

// ---------------------------------------------------------------------------

extern "C" void kernel_launch(void* const* d_in, const int* in_sizes, int n_in,
                              void* d_out, int out_size, void* d_ws, size_t ws_size,
                              hipStream_t stream) {
    const float* dxyzp = (const float*)d_in[0];   // (B,S,4)
    const float* dfeat = (const float*)d_in[1];   // (B,S,256)
    const float* oxyzp = (const float*)d_in[2];   // (B,N,4)
    const float* ofeat = (const float*)d_in[3];   // (B,N,128)
    const float* W1    = (const float*)d_in[4];   // (256,128)
    const float* b1    = (const float*)d_in[5];   // (128)
    const float* W2    = (const float*)d_in[6];   // (128,128)
    const float* b2    = (const float*)d_in[7];   // (128)

    float* out   = (float*)d_out;                 // (B,N,128)
    float* downf = (float*)d_ws;                  // (B,S,128) scratch: 4 MB

    // down_f = down_features @ W1 + b1  -> workspace  (MFMA bf16)
    k_mfma<INC, 32><<<(B * S) / 32, 256, 0, stream>>>(dfeat, W1, b1, downf);
    // ori_f = ori_features @ W2 + b2    -> out        (MFMA bf16)
    k_mfma<OUTC, 64><<<(B * N) / 64, 256, 0, stream>>>(ofeat, W2, b2, out);
    // out += 3-NN inverse-distance interpolation of down_f
    k_interp<<<B * (N / 32), 256, 0, stream>>>(
        (const float4*)dxyzp, (const float4*)oxyzp, downf, out);
}

// Round 7
// 115.390 us; speedup vs baseline: 1.2065x; 1.0051x over previous
//
#include <hip/hip_runtime.h>
#include <hip/hip_bf16.h>
#include <float.h>

// Problem constants
constexpr int B   = 2;
constexpr int N   = 16384;
constexpr int S   = 4096;
constexpr int INC = 256;
constexpr int OUTC = 128;

typedef short short4_t __attribute__((ext_vector_type(4)));
typedef short short8_t __attribute__((ext_vector_type(8)));
typedef float f32x4    __attribute__((ext_vector_type(4)));

__device__ __forceinline__ unsigned short f2bf(float f) {
    unsigned u = __builtin_bit_cast(unsigned, f);
    u += 0x7fffu + ((u >> 16) & 1u);          // round-to-nearest-even
    return (unsigned short)(u >> 16);
}

// ---------------------------------------------------------------------------
// MFMA GEMM (unchanged from passing R6): out = f @ W + bias, bf16/fp32-acc.
// ---------------------------------------------------------------------------
template <int K, int ROWS>
__global__ __launch_bounds__(256) void k_mfma(const float* __restrict__ f,
                                              const float* __restrict__ W,
                                              const float* __restrict__ bias,
                                              float* __restrict__ outf) {
    constexpr int MF = ROWS / 16;             // row fragments per wave
    constexpr int KS = K / 32;                // k steps
    __shared__ __align__(16) short smem[K * 128];   // W stage, then A tile

    const int tid  = threadIdx.x;
    const int lane = tid & 63;
    const int wv   = tid >> 6;
    const int rowbase = blockIdx.x * ROWS;
    const int lo16 = lane & 15;
    const int hi8  = (lane >> 4) * 8;

    // ---- stage W (bf16, row-major [K][128]) ----
    const float4* w4 = reinterpret_cast<const float4*>(W);
    for (int n = tid; n < K * 32; n += 256) {       // K*128/4 float4s
        const float4 u = w4[n];
        short4_t s = { (short)f2bf(u.x), (short)f2bf(u.y),
                       (short)f2bf(u.z), (short)f2bf(u.w) };
        *reinterpret_cast<short4_t*>(&smem[n * 4]) = s;
    }
    __syncthreads();

    // ---- build B fragments in registers (live for the whole block) ----
    short8_t bf[KS][2];
    #pragma unroll
    for (int ks = 0; ks < KS; ++ks) {
        #pragma unroll
        for (int c = 0; c < 2; ++c) {
            const int col = wv * 32 + c * 16 + lo16;
            #pragma unroll
            for (int r = 0; r < 8; ++r)
                bf[ks][c][r] = smem[(ks * 32 + hi8 + r) * 128 + col];
        }
    }
    __syncthreads();                                 // W area now dead

    // ---- stage A tile (bf16, [ROWS][K], XOR-swizzled) ----
    const float4* a4 = reinterpret_cast<const float4*>(f + (size_t)rowbase * K);
    for (int n = tid; n < ROWS * K / 8; n += 256) {
        const int row   = n / (K / 8);
        const int k8    = (n % (K / 8)) * 8;
        const int base4 = (row * K + k8) >> 2;
        const float4 u = a4[base4];
        const float4 v = a4[base4 + 1];
        short8_t s = { (short)f2bf(u.x), (short)f2bf(u.y), (short)f2bf(u.z), (short)f2bf(u.w),
                       (short)f2bf(v.x), (short)f2bf(v.y), (short)f2bf(v.z), (short)f2bf(v.w) };
        const int idx = (row * K + k8) ^ ((row & 7) << 3);   // short-index XOR
        *reinterpret_cast<short8_t*>(&smem[idx]) = s;
    }
    __syncthreads();

    // ---- MFMA main loop ----
    f32x4 acc[MF][2];
    #pragma unroll
    for (int m = 0; m < MF; ++m) {
        #pragma unroll
        for (int c = 0; c < 2; ++c) acc[m][c] = (f32x4){0.f, 0.f, 0.f, 0.f};
    }

    const int axor = (lane & 7) << 3;   // row&7 == lane&7 since row = m*16+lo16
    #pragma unroll
    for (int ks = 0; ks < KS; ++ks) {
        #pragma unroll
        for (int m = 0; m < MF; ++m) {
            const int aidx = ((m * 16 + lo16) * K + ks * 32 + hi8) ^ axor;
            const short8_t af = *reinterpret_cast<const short8_t*>(&smem[aidx]);
            acc[m][0] = __builtin_amdgcn_mfma_f32_16x16x32_bf16(af, bf[ks][0], acc[m][0], 0, 0, 0);
            acc[m][1] = __builtin_amdgcn_mfma_f32_16x16x32_bf16(af, bf[ks][1], acc[m][1], 0, 0, 0);
        }
    }

    // ---- epilogue: D[(l>>4)*4+r][l&15] + bias ----
    #pragma unroll
    for (int c = 0; c < 2; ++c) {
        const int col = wv * 32 + c * 16 + lo16;
        const float bb = bias[col];
        #pragma unroll
        for (int m = 0; m < MF; ++m) {
            #pragma unroll
            for (int r = 0; r < 4; ++r) {
                const int row = rowbase + m * 16 + (lane >> 4) * 4 + r;
                outf[(size_t)row * 128 + col] = acc[m][c][r] + bb;
            }
        }
    }
}

// ---------------------------------------------------------------------------
// K3 — occupancy build: 16 queries/block -> grid 2048 (8 blocks/CU),
// LDS chunk = 1024 candidates (16.6 KB) -> 8 blocks resident, 8 waves/SIMD.
//   lane: sp = lane&15 (16 candidate sub-ranges), qs = lane>>4,
//   slot = wave*4+qs (0..15). 4 chunks of 1024; per chunk each lane scans
//   sub-array sp (64 candidates), ascending global index across chunks ->
//   strict-'<' INS3M tie-stable (R3/R5-proven).
//   Butterfly m=1,2,4,8 with LEXICOGRAPHIC INS3L (order-independent, proven).
// Staged candidates PRE-DOUBLED (2x,2y,2z,sumsq) -> dd bit-exact vs numpy
// (validated R3/R5/R6). Sub-array stride 65 float4: 16 broadcast reads land
// on 8 bank-quads = 2-way aliasing (free per m136).
// ---------------------------------------------------------------------------
#define INS3M(d0, d1, d2, i0, i1, i2, dd, ss)                               \
    {                                                                       \
        const bool c0 = (dd) < d0, c1 = (dd) < d1, c2 = (dd) < d2;          \
        i2 = c1 ? i1 : (c2 ? (ss) : i2);                                    \
        i1 = c0 ? i0 : (c1 ? (ss) : i1);                                    \
        i0 = c0 ? (ss) : i0;                                                \
        d2 = fminf(fmaxf((dd), d1), d2);                                    \
        d1 = fminf(fmaxf((dd), d0), d1);                                    \
        d0 = fminf(d0, (dd));                                               \
    }

#define INS3L(d0, d1, d2, i0, i1, i2, dd, ss)                               \
    {                                                                       \
        const bool c0 = ((dd) < d0) | (((dd) == d0) & ((ss) < i0));         \
        const bool c1 = ((dd) < d1) | (((dd) == d1) & ((ss) < i1));         \
        const bool c2 = ((dd) < d2) | (((dd) == d2) & ((ss) < i2));         \
        i2 = c1 ? i1 : (c2 ? (ss) : i2);                                    \
        i1 = c0 ? i0 : (c1 ? (ss) : i1);                                    \
        i0 = c0 ? (ss) : i0;                                                \
        d2 = c1 ? d1 : (c2 ? (dd) : d2);                                    \
        d1 = c0 ? d0 : (c1 ? (dd) : d1);                                    \
        d0 = c0 ? (dd) : d0;                                                \
    }

__global__ __launch_bounds__(256) void k_interp(const float4* __restrict__ dxyzp,
                                                const float4* __restrict__ oxyzp,
                                                const float*  __restrict__ downf,
                                                float*        __restrict__ out) {
    // 16 sub-ranges x (64 + 1 skew) float4 = 16640 B
    __shared__ float4 sx[16 * 65];
    __shared__ int    si[16 * 3];
    __shared__ float  sw[16 * 3];

    const int b     = blockIdx.x >> 10;           // 1024 blocks per batch
    const int qbase = (blockIdx.x & 1023) * 16;

    const int lane = threadIdx.x & 63;
    const int wave = threadIdx.x >> 6;
    const int sp   = lane & 15;
    const int qs   = lane >> 4;
    const int slot = wave * 4 + qs;               // 0..15 within block

    const float4 o = oxyzp[(size_t)b * N + qbase + slot];
    const float sumo = __fadd_rn(__fadd_rn(__fmul_rn(o.x, o.x), __fmul_rn(o.y, o.y)),
                                 __fmul_rn(o.z, o.z));

    float a0 = FLT_MAX, a1 = FLT_MAX, a2 = FLT_MAX;
    int   ai0 = 0, ai1 = 0, ai2 = 0;

    const float4* dpb = dxyzp + (size_t)b * S;

    for (int c = 0; c < 4; ++c) {
        if (c > 0) __syncthreads();               // all waves done with prev chunk

        // Stage chunk c: (2x, 2y, 2z, x^2+y^2+z^2); doubling is exact.
        const float4* dpc = dpb + c * 1024;
        for (int j = threadIdx.x; j < 1024; j += 256) {
            float4 v = dpc[j];
            const float ss = __fadd_rn(__fadd_rn(__fmul_rn(v.x, v.x), __fmul_rn(v.y, v.y)),
                                       __fmul_rn(v.z, v.z));
            float4 w;
            w.x = v.x + v.x;
            w.y = v.y + v.y;
            w.z = v.z + v.z;
            w.w = ss;
            sx[(j >> 6) * 65 + (j & 63)] = w;
        }
        __syncthreads();

        const float4* base = &sx[sp * 65];
        const int g0 = c * 1024 + sp * 64;        // ascending across chunks

        #pragma unroll 4
        for (int i = 0; i < 64; ++i) {
            const float4 q = base[i];
            const float dot2 = __fadd_rn(__fadd_rn(__fmul_rn(q.x, o.x), __fmul_rn(q.y, o.y)),
                                         __fmul_rn(q.z, o.z));
            const float dd = __fsub_rn(__fadd_rn(sumo, q.w), dot2);
            INS3M(a0, a1, a2, ai0, ai1, ai2, dd, g0 + i);
        }
    }

    // Butterfly merge across the 16 sp-groups, lexicographic.
    #pragma unroll
    for (int m = 1; m <= 8; m <<= 1) {
        const float nd0 = __shfl_xor(a0, m, 64);
        const float nd1 = __shfl_xor(a1, m, 64);
        const float nd2 = __shfl_xor(a2, m, 64);
        const int   ni0 = __shfl_xor(ai0, m, 64);
        const int   ni1 = __shfl_xor(ai1, m, 64);
        const int   ni2 = __shfl_xor(ai2, m, 64);
        INS3L(a0, a1, a2, ai0, ai1, ai2, nd0, ni0);
        INS3L(a0, a1, a2, ai0, ai1, ai2, nd1, ni1);
        INS3L(a0, a1, a2, ai0, ai1, ai2, nd2, ni2);
    }

    if (sp == 0) {
        const float r0 = 1.0f / (a0 + 1e-8f);
        const float r1 = 1.0f / (a1 + 1e-8f);
        const float r2 = 1.0f / (a2 + 1e-8f);
        const float rs = __fadd_rn(__fadd_rn(r0, r1), r2);
        si[slot * 3 + 0] = ai0;
        si[slot * 3 + 1] = ai1;
        si[slot * 3 + 2] = ai2;
        sw[slot * 3 + 0] = r0 / rs;
        sw[slot * 3 + 1] = r1 / rs;
        sw[slot * 3 + 2] = r2 / rs;
    }
    __syncthreads();

    // Gather + interpolate: 16 points x 128 channels, 256 threads.
    const int ch = threadIdx.x & 127;
    const int hf = threadIdx.x >> 7;
    const float* df = downf + (size_t)b * S * OUTC;
    float* ob = out + ((size_t)b * N + qbase) * OUTC;

    for (int pp = hf; pp < 16; pp += 2) {
        const int   j0 = si[pp * 3 + 0];
        const int   j1 = si[pp * 3 + 1];
        const int   j2 = si[pp * 3 + 2];
        const float w0 = sw[pp * 3 + 0];
        const float w1 = sw[pp * 3 + 1];
        const float w2 = sw[pp * 3 + 2];
        const float g = __fadd_rn(
            __fadd_rn(__fmul_rn(w0, df[(size_t)j0 * OUTC + ch]),
                      __fmul_rn(w1, df[(size_t)j1 * OUTC + ch])),
            __fmul_rn(w2, df[(size_t)j2 * OUTC + ch]));
        ob[(size_t)pp * OUTC + ch] += g;
    }
}

// ---------------------------------------------------------------------------

extern "C" void kernel_launch(void* const* d_in, const int* in_sizes, int n_in,
                              void* d_out, int out_size, void* d_ws, size_t ws_size,
                              hipStream_t stream) {
    const float* dxyzp = (const float*)d_in[0];   // (B,S,4)
    const float* dfeat = (const float*)d_in[1];   // (B,S,256)
    const float* oxyzp = (const float*)d_in[2];   // (B,N,4)
    const float* ofeat = (const float*)d_in[3];   // (B,N,128)
    const float* W1    = (const float*)d_in[4];   // (256,128)
    const float* b1    = (const float*)d_in[5];   // (128)
    const float* W2    = (const float*)d_in[6];   // (128,128)
    const float* b2    = (const float*)d_in[7];   // (128)

    float* out   = (float*)d_out;                 // (B,N,128)
    float* downf = (float*)d_ws;                  // (B,S,128) scratch: 4 MB

    // down_f = down_features @ W1 + b1  -> workspace  (MFMA bf16)
    k_mfma<INC, 32><<<(B * S) / 32, 256, 0, stream>>>(dfeat, W1, b1, downf);
    // ori_f = ori_features @ W2 + b2    -> out        (MFMA bf16)
    k_mfma<OUTC, 64><<<(B * N) / 64, 256, 0, stream>>>(ofeat, W2, b2, out);
    // out += 3-NN inverse-distance interpolation of down_f
    k_interp<<<B * (N / 16), 256, 0, stream>>>(
        (const float4*)dxyzp, (const float4*)oxyzp, downf, out);
}